// Round 1
// baseline (2122.795 us; speedup 1.0000x reference)
//
#include <hip/hip_runtime.h>
#include <hip/hip_bf16.h>
#include <math.h>

#define D_MODEL 768
#define D_STATE 16
#define D_CONV  4
#define D_INNER 1536
#define DT_RANK 48
#define BATCH   2
#define SEQ     2048
#define BL      (BATCH*SEQ)          // 4096 rows
#define XZ_W    (2*D_INNER)          // 3072
#define SSM_W   (DT_RANK + 2*D_STATE) // 80

__device__ __forceinline__ float silu_f(float x) { return x / (1.f + __expf(-x)); }
__device__ __forceinline__ float softplus_f(float x) {
    // jax.nn.softplus = logaddexp(x, 0) = max(x,0) + log1p(exp(-|x|))
    return fmaxf(x, 0.f) + log1pf(__expf(-fabsf(x)));
}

// ---------------- generic fp32 tiled GEMM: C[M,N] = A[M,K]*B[K,N] ----------------
// 64x64 tile, 256 threads, 4x4 micro-tile per thread, K-step 16.
// M (grid.y*64) must be multiple of 64; K multiple of 16; N ragged allowed (guarded).
// epilogue: 0 = plain store, 1 = softplus(acc + bias[col])
__global__ __launch_bounds__(256)
void gemm_f32(const float* __restrict__ A, const float* __restrict__ B,
              float* __restrict__ C, const float* __restrict__ bias,
              int N, int K, int lda, int ldb, int ldc, int epilogue)
{
    __shared__ float As[16][64];   // [k][m]
    __shared__ float Bs[16][64];   // [k][n]
    const int tid = threadIdx.x;
    const int m0 = blockIdx.y * 64;
    const int n0 = blockIdx.x * 64;
    const int tx = tid & 15, ty = tid >> 4;
    const int a_row = tid >> 2;            // 0..63
    const int a_k4  = (tid & 3) << 2;      // 0,4,8,12
    const int b_k   = tid >> 4;            // 0..15
    const int b_n4  = (tid & 15) << 2;     // 0..60
    const bool full_n = (n0 + 64) <= N;

    float acc[4][4] = {};

    for (int k0 = 0; k0 < K; k0 += 16) {
        float4 av = *(const float4*)(A + (size_t)(m0 + a_row) * lda + (k0 + a_k4));
        As[a_k4 + 0][a_row] = av.x;
        As[a_k4 + 1][a_row] = av.y;
        As[a_k4 + 2][a_row] = av.z;
        As[a_k4 + 3][a_row] = av.w;
        if (full_n) {
            *(float4*)&Bs[b_k][b_n4] =
                *(const float4*)(B + (size_t)(k0 + b_k) * ldb + (n0 + b_n4));
        } else {
            #pragma unroll
            for (int j = 0; j < 4; ++j) {
                int col = n0 + b_n4 + j;
                Bs[b_k][b_n4 + j] = (col < N) ? B[(size_t)(k0 + b_k) * ldb + col] : 0.f;
            }
        }
        __syncthreads();
        #pragma unroll
        for (int kk = 0; kk < 16; ++kk) {
            float a[4], bb[4];
            #pragma unroll
            for (int i = 0; i < 4; ++i) a[i]  = As[kk][ty * 4 + i];
            #pragma unroll
            for (int j = 0; j < 4; ++j) bb[j] = Bs[kk][tx * 4 + j];
            #pragma unroll
            for (int i = 0; i < 4; ++i)
                #pragma unroll
                for (int j = 0; j < 4; ++j)
                    acc[i][j] = fmaf(a[i], bb[j], acc[i][j]);
        }
        __syncthreads();
    }

    #pragma unroll
    for (int i = 0; i < 4; ++i) {
        size_t row = (size_t)(m0 + ty * 4 + i);
        #pragma unroll
        for (int j = 0; j < 4; ++j) {
            int col = n0 + tx * 4 + j;
            if (full_n || col < N) {
                float v = acc[i][j];
                if (epilogue == 1) v = softplus_f(v + bias[col]);
                C[row * ldc + col] = v;
            }
        }
    }
}

// ---------------- depthwise causal conv1d(4) + bias + SiLU ----------------
// reads u part of xz ([BL,3072] cols 0..1535), writes uc [BL,1536]
__global__ __launch_bounds__(256)
void conv_silu(const float* __restrict__ xz, const float* __restrict__ cw,
               const float* __restrict__ cb, float* __restrict__ uc)
{
    int idx = blockIdx.x * 256 + threadIdx.x;      // over BL*D_INNER
    int e  = idx % D_INNER;
    int bt = idx / D_INNER;                        // 0..BL-1
    int t  = bt % SEQ;
    const float* base = xz + (size_t)bt * XZ_W + e;
    float w0 = cw[e * 4 + 0], w1 = cw[e * 4 + 1], w2 = cw[e * 4 + 2], w3 = cw[e * 4 + 3];
    float acc = cb[e] + w3 * base[0];              // k=3 -> in[t]
    if (t >= 1) acc = fmaf(w2, base[-(int)XZ_W], acc);
    if (t >= 2) acc = fmaf(w1, base[-2 * (int)XZ_W], acc);
    if (t >= 3) acc = fmaf(w0, base[-3 * (int)XZ_W], acc);
    uc[(size_t)bt * D_INNER + e] = silu_f(acc);
}

// ---------------- sequential SSM scan ----------------
// One 16-lane group per (b, e): lane n holds h[n]. Block = 128 thr = 8 channels.
// y = (sum_n h*C + u*Dp) * silu(res), written to yout[bt*1536+e].
// NOTE: dt/yout may alias (same buffer) -- safe: all 16 lanes read dt[bt,e]
// before lane 0 stores yout[bt,e] (value-dependent, same wave). No __restrict__.
__global__ __launch_bounds__(128)
void ssm_scan(const float* dt, const float* __restrict__ uc,
              const float* __restrict__ smb, const float* __restrict__ xz,
              const float* __restrict__ A_log, const float* __restrict__ Dp,
              float* yout)
{
    const int tid = threadIdx.x;
    const int n   = tid & 15;
    const int eg  = blockIdx.x % (D_INNER / 8);
    const int b   = blockIdx.x / (D_INNER / 8);
    const int e   = eg * 8 + (tid >> 4);

    const float Av = -__expf(A_log[e * D_STATE + n]);
    const float Dv = Dp[e];
    float h = 0.f;
    const size_t bofs = (size_t)b * SEQ;

    for (int t = 0; t < SEQ; ++t) {
        size_t r = bofs + t;
        float dt_v = dt[r * D_INNER + e];
        float u_v  = uc[r * D_INNER + e];
        float Bv   = smb[r * SSM_W + DT_RANK + n];
        float Cv   = smb[r * SSM_W + DT_RANK + D_STATE + n];
        float dA   = __expf(dt_v * Av);
        h = fmaf(dA, h, dt_v * Bv * u_v);
        float p = h * Cv;
        p += __shfl_xor(p, 8, 16);
        p += __shfl_xor(p, 4, 16);
        p += __shfl_xor(p, 2, 16);
        p += __shfl_xor(p, 1, 16);
        if (n == 0) {
            float res = xz[r * XZ_W + D_INNER + e];
            float y = fmaf(u_v, Dv, p) * silu_f(res);
            yout[r * D_INNER + e] = y;
        }
    }
}

extern "C" void kernel_launch(void* const* d_in, const int* in_sizes, int n_in,
                              void* d_out, int out_size, void* d_ws, size_t ws_size,
                              hipStream_t stream)
{
    const float* x      = (const float*)d_in[0];
    const float* W_in   = (const float*)d_in[1];
    const float* conv_w = (const float*)d_in[2];
    const float* conv_b = (const float*)d_in[3];
    const float* W_x    = (const float*)d_in[4];
    const float* W_dt   = (const float*)d_in[5];
    const float* b_dt   = (const float*)d_in[6];
    const float* A_log  = (const float*)d_in[7];
    const float* Dp     = (const float*)d_in[8];
    const float* W_out  = (const float*)d_in[9];
    float* out = (float*)d_out;

    // workspace layout (bytes), all 16B-aligned:
    //   xz  @ 0          : 4096*3072*4 = 50,331,648
    //   uc  @ 50331648   : 4096*1536*4 = 25,165,824
    //   smb @ 75497472   : 4096*80*4   =  1,310,720
    //   dtb @ 76808192   : 4096*1536*4 = 25,165,824
    //   yf  @ 101974016  : 4096*1536*4 = 25,165,824   (fallback: alias dtb)
    char*  ws  = (char*)d_ws;
    float* xz  = (float*)(ws);
    float* uc  = (float*)(ws + 50331648);
    float* smb = (float*)(ws + 75497472);
    float* dtb = (float*)(ws + 76808192);
    float* yf  = (ws_size >= (size_t)127139840) ? (float*)(ws + 101974016) : dtb;

    // 1) xz = x @ W_in                     [4096,3072] K=768
    gemm_f32<<<dim3(XZ_W / 64, BL / 64), 256, 0, stream>>>(
        x, W_in, xz, nullptr, XZ_W, D_MODEL, D_MODEL, XZ_W, XZ_W, 0);

    // 2) depthwise causal conv + SiLU -> uc [4096,1536]
    conv_silu<<<(BL * D_INNER) / 256, 256, 0, stream>>>(xz, conv_w, conv_b, uc);

    // 3) ssm = uc @ W_x                    [4096,80] K=1536 (ragged N)
    gemm_f32<<<dim3(2, BL / 64), 256, 0, stream>>>(
        uc, W_x, smb, nullptr, SSM_W, D_INNER, D_INNER, SSM_W, SSM_W, 0);

    // 4) dt = softplus(ssm[:, :48] @ W_dt + b_dt)  [4096,1536] K=48
    gemm_f32<<<dim3(D_INNER / 64, BL / 64), 256, 0, stream>>>(
        smb, W_dt, dtb, b_dt, D_INNER, DT_RANK, SSM_W, D_INNER, D_INNER, 1);

    // 5) sequential SSM scan -> yf [4096,1536] (fused +u*Dp and *silu(res))
    ssm_scan<<<BATCH * (D_INNER / 8), 128, 0, stream>>>(
        dtb, uc, smb, xz, A_log, Dp, yf);

    // 6) out = yf @ W_out                  [4096,768] K=1536
    gemm_f32<<<dim3(D_MODEL / 64, BL / 64), 256, 0, stream>>>(
        yf, W_out, out, nullptr, D_MODEL, D_INNER, D_INNER, D_MODEL, D_MODEL, 0);
}

// Round 2
// 904.974 us; speedup vs baseline: 2.3457x; 2.3457x over previous
//
#include <hip/hip_runtime.h>
#include <hip/hip_bf16.h>
#include <math.h>

#define D_MODEL 768
#define D_STATE 16
#define D_CONV  4
#define D_INNER 1536
#define DT_RANK 48
#define BATCH   2
#define SEQ     2048
#define BL      (BATCH*SEQ)          // 4096 rows
#define XZ_W    (2*D_INNER)          // 3072
#define SSM_W   (DT_RANK + 2*D_STATE) // 80

#define CH      32                   // time chunks
#define CT      (SEQ/CH)             // 64 steps per chunk
#define NREC    (BATCH*D_INNER*D_STATE) // 49152 independent recurrences

__device__ __forceinline__ float silu_f(float x) { return x / (1.f + __expf(-x)); }
__device__ __forceinline__ float softplus_f(float x) {
    return fmaxf(x, 0.f) + log1pf(__expf(-fabsf(x)));
}

// ---------------- generic fp32 tiled GEMM: C[M,N] = A[M,K]*B[K,N] ----------------
__global__ __launch_bounds__(256)
void gemm_f32(const float* __restrict__ A, const float* __restrict__ B,
              float* __restrict__ C, const float* __restrict__ bias,
              int N, int K, int lda, int ldb, int ldc, int epilogue)
{
    __shared__ float As[16][64];   // [k][m]
    __shared__ float Bs[16][64];   // [k][n]
    const int tid = threadIdx.x;
    const int m0 = blockIdx.y * 64;
    const int n0 = blockIdx.x * 64;
    const int tx = tid & 15, ty = tid >> 4;
    const int a_row = tid >> 2;
    const int a_k4  = (tid & 3) << 2;
    const int b_k   = tid >> 4;
    const int b_n4  = (tid & 15) << 2;
    const bool full_n = (n0 + 64) <= N;

    float acc[4][4] = {};

    for (int k0 = 0; k0 < K; k0 += 16) {
        float4 av = *(const float4*)(A + (size_t)(m0 + a_row) * lda + (k0 + a_k4));
        As[a_k4 + 0][a_row] = av.x;
        As[a_k4 + 1][a_row] = av.y;
        As[a_k4 + 2][a_row] = av.z;
        As[a_k4 + 3][a_row] = av.w;
        if (full_n) {
            *(float4*)&Bs[b_k][b_n4] =
                *(const float4*)(B + (size_t)(k0 + b_k) * ldb + (n0 + b_n4));
        } else {
            #pragma unroll
            for (int j = 0; j < 4; ++j) {
                int col = n0 + b_n4 + j;
                Bs[b_k][b_n4 + j] = (col < N) ? B[(size_t)(k0 + b_k) * ldb + col] : 0.f;
            }
        }
        __syncthreads();
        #pragma unroll
        for (int kk = 0; kk < 16; ++kk) {
            float a[4], bb[4];
            #pragma unroll
            for (int i = 0; i < 4; ++i) a[i]  = As[kk][ty * 4 + i];
            #pragma unroll
            for (int j = 0; j < 4; ++j) bb[j] = Bs[kk][tx * 4 + j];
            #pragma unroll
            for (int i = 0; i < 4; ++i)
                #pragma unroll
                for (int j = 0; j < 4; ++j)
                    acc[i][j] = fmaf(a[i], bb[j], acc[i][j]);
        }
        __syncthreads();
    }

    #pragma unroll
    for (int i = 0; i < 4; ++i) {
        size_t row = (size_t)(m0 + ty * 4 + i);
        #pragma unroll
        for (int j = 0; j < 4; ++j) {
            int col = n0 + tx * 4 + j;
            if (full_n || col < N) {
                float v = acc[i][j];
                if (epilogue == 1) v = softplus_f(v + bias[col]);
                C[row * ldc + col] = v;
            }
        }
    }
}

// ---------------- depthwise causal conv1d(4) + bias + SiLU ----------------
__global__ __launch_bounds__(256)
void conv_silu(const float* __restrict__ xz, const float* __restrict__ cw,
               const float* __restrict__ cb, float* __restrict__ uc)
{
    int idx = blockIdx.x * 256 + threadIdx.x;
    int e  = idx % D_INNER;
    int bt = idx / D_INNER;
    int t  = bt % SEQ;
    const float* base = xz + (size_t)bt * XZ_W + e;
    float w0 = cw[e * 4 + 0], w1 = cw[e * 4 + 1], w2 = cw[e * 4 + 2], w3 = cw[e * 4 + 3];
    float acc = cb[e] + w3 * base[0];
    if (t >= 1) acc = fmaf(w2, base[-(int)XZ_W], acc);
    if (t >= 2) acc = fmaf(w1, base[-2 * (int)XZ_W], acc);
    if (t >= 3) acc = fmaf(w0, base[-3 * (int)XZ_W], acc);
    uc[(size_t)bt * D_INNER + e] = silu_f(acc);
}

// ---------------- chunked parallel SSM scan ----------------
// Pass 1: per (b, chunk, e-group): local scan with h0=0; emit P = prod(dA)
// and h_end per (b,e,n,chunk). 16 lanes per channel (lane = n), 8 ch/block.
__global__ __launch_bounds__(128)
void scan_pass1(const float* __restrict__ dt, const float* __restrict__ uc,
                const float* __restrict__ smb, const float* __restrict__ A_log,
                float* __restrict__ Pbuf, float* __restrict__ Hend)
{
    const int tid = threadIdx.x;
    const int n   = tid & 15;
    const int eg  = blockIdx.x % (D_INNER / 8);
    const int c   = (blockIdx.x / (D_INNER / 8)) % CH;
    const int b   = blockIdx.x / ((D_INNER / 8) * CH);
    const int e   = eg * 8 + (tid >> 4);

    const float Av = -__expf(A_log[e * D_STATE + n]);
    float h = 0.f, P = 1.f;
    const size_t base = (size_t)b * SEQ + (size_t)c * CT;

    for (int t = 0; t < CT; ++t) {
        size_t r = base + t;
        float dt_v = dt[r * D_INNER + e];
        float u_v  = uc[r * D_INNER + e];
        float Bv   = smb[r * SSM_W + DT_RANK + n];
        float dA   = __expf(dt_v * Av);
        h = fmaf(dA, h, dt_v * Bv * u_v);
        P *= dA;
    }
    size_t i = (size_t)(b * D_INNER + e) * D_STATE + n;   // 0..NREC-1
    Pbuf[(size_t)c * NREC + i] = P;
    Hend[(size_t)c * NREC + i] = h;
}

// Pass 2: sequential combine over chunks; one thread per (b,e,n).
// Rewrites Pbuf[c] slot with the chunk's true START state.
__global__ __launch_bounds__(256)
void scan_pass2(float* __restrict__ Pbuf, float* __restrict__ Hend)
{
    size_t i = (size_t)blockIdx.x * 256 + threadIdx.x;    // 0..NREC-1
    float H = 0.f;
    for (int c = 0; c < CH; ++c) {
        size_t o = (size_t)c * NREC + i;
        float P  = Pbuf[o];
        float he = Hend[o];
        Pbuf[o] = H;                 // h at chunk start
        H = fmaf(P, H, he);
    }
}

// Pass 3: rerun recurrence per chunk with true start state; emit y.
// dt/yout may alias (ws fallback): all lanes read dt[r,e] before lane 0
// writes yout[r,e] in the same wave-iteration -- safe. No __restrict__ on those.
__global__ __launch_bounds__(128)
void scan_pass3(const float* dt, const float* __restrict__ uc,
                const float* __restrict__ smb, const float* __restrict__ xz,
                const float* __restrict__ A_log, const float* __restrict__ Dp,
                const float* __restrict__ Hstart, float* yout)
{
    const int tid = threadIdx.x;
    const int n   = tid & 15;
    const int eg  = blockIdx.x % (D_INNER / 8);
    const int c   = (blockIdx.x / (D_INNER / 8)) % CH;
    const int b   = blockIdx.x / ((D_INNER / 8) * CH);
    const int e   = eg * 8 + (tid >> 4);

    const float Av = -__expf(A_log[e * D_STATE + n]);
    const float Dv = Dp[e];
    size_t i = (size_t)(b * D_INNER + e) * D_STATE + n;
    float h = Hstart[(size_t)c * NREC + i];
    const size_t base = (size_t)b * SEQ + (size_t)c * CT;

    for (int t = 0; t < CT; ++t) {
        size_t r = base + t;
        float dt_v = dt[r * D_INNER + e];
        float u_v  = uc[r * D_INNER + e];
        float Bv   = smb[r * SSM_W + DT_RANK + n];
        float Cv   = smb[r * SSM_W + DT_RANK + D_STATE + n];
        float dA   = __expf(dt_v * Av);
        h = fmaf(dA, h, dt_v * Bv * u_v);
        float p = h * Cv;
        p += __shfl_xor(p, 8, 16);
        p += __shfl_xor(p, 4, 16);
        p += __shfl_xor(p, 2, 16);
        p += __shfl_xor(p, 1, 16);
        if (n == 0) {
            float res = xz[r * XZ_W + D_INNER + e];
            float y = fmaf(u_v, Dv, p) * silu_f(res);
            yout[r * D_INNER + e] = y;
        }
    }
}

extern "C" void kernel_launch(void* const* d_in, const int* in_sizes, int n_in,
                              void* d_out, int out_size, void* d_ws, size_t ws_size,
                              hipStream_t stream)
{
    const float* x      = (const float*)d_in[0];
    const float* W_in   = (const float*)d_in[1];
    const float* conv_w = (const float*)d_in[2];
    const float* conv_b = (const float*)d_in[3];
    const float* W_x    = (const float*)d_in[4];
    const float* W_dt   = (const float*)d_in[5];
    const float* b_dt   = (const float*)d_in[6];
    const float* A_log  = (const float*)d_in[7];
    const float* Dp     = (const float*)d_in[8];
    const float* W_out  = (const float*)d_in[9];
    float* out = (float*)d_out;

    // workspace layout (bytes):
    //   xz  @ 0          : 50,331,648
    //   uc  @ 50331648   : 25,165,824
    //   smb @ 75497472   :  1,310,720
    //   dtb @ 76808192   : 25,165,824
    //   yf  @ 101974016  : 25,165,824   (fallback: alias dtb)
    char*  ws  = (char*)d_ws;
    float* xz  = (float*)(ws);
    float* uc  = (float*)(ws + 50331648);
    float* smb = (float*)(ws + 75497472);
    float* dtb = (float*)(ws + 76808192);
    float* yf  = (ws_size >= (size_t)127139840) ? (float*)(ws + 101974016) : dtb;

    // chunk-state buffers live in d_out (dead until final GEMM):
    // Pbuf = CH*NREC floats (6,291,456 B), Hend = same. Exactly out_size.
    float* Pbuf = out;
    float* Hend = out + (size_t)CH * NREC;

    // 1) xz = x @ W_in                     [4096,3072] K=768
    gemm_f32<<<dim3(XZ_W / 64, BL / 64), 256, 0, stream>>>(
        x, W_in, xz, nullptr, XZ_W, D_MODEL, D_MODEL, XZ_W, XZ_W, 0);

    // 2) depthwise causal conv + SiLU -> uc [4096,1536]
    conv_silu<<<(BL * D_INNER) / 256, 256, 0, stream>>>(xz, conv_w, conv_b, uc);

    // 3) ssm = uc @ W_x                    [4096,80] K=1536
    gemm_f32<<<dim3(2, BL / 64), 256, 0, stream>>>(
        uc, W_x, smb, nullptr, SSM_W, D_INNER, D_INNER, SSM_W, SSM_W, 0);

    // 4) dt = softplus(ssm[:, :48] @ W_dt + b_dt)  [4096,1536] K=48
    gemm_f32<<<dim3(D_INNER / 64, BL / 64), 256, 0, stream>>>(
        smb, W_dt, dtb, b_dt, D_INNER, DT_RANK, SSM_W, D_INNER, D_INNER, 1);

    // 5) chunked parallel scan
    scan_pass1<<<BATCH * CH * (D_INNER / 8), 128, 0, stream>>>(
        dtb, uc, smb, A_log, Pbuf, Hend);
    scan_pass2<<<NREC / 256, 256, 0, stream>>>(Pbuf, Hend);
    scan_pass3<<<BATCH * CH * (D_INNER / 8), 128, 0, stream>>>(
        dtb, uc, smb, xz, A_log, Dp, Pbuf, yf);

    // 6) out = yf @ W_out                  [4096,768] K=1536
    gemm_f32<<<dim3(D_MODEL / 64, BL / 64), 256, 0, stream>>>(
        yf, W_out, out, nullptr, D_MODEL, D_INNER, D_INNER, D_MODEL, D_MODEL, 0);
}

// Round 3
// 591.102 us; speedup vs baseline: 3.5913x; 1.5310x over previous
//
#include <hip/hip_runtime.h>
#include <hip/hip_bf16.h>
#include <math.h>

#define D_MODEL 768
#define D_STATE 16
#define D_CONV  4
#define D_INNER 1536
#define DT_RANK 48
#define BATCH   2
#define SEQ     2048
#define BL      (BATCH*SEQ)          // 4096 rows
#define XZ_W    (2*D_INNER)          // 3072
#define SSM_W   (DT_RANK + 2*D_STATE) // 80

#define CH      32                   // time chunks
#define CT      (SEQ/CH)             // 64 steps per chunk
#define NREC    (BATCH*D_INNER*D_STATE) // 49152 independent recurrences

typedef __attribute__((ext_vector_type(8))) short short8;   // 8 bf16 (4 VGPRs)
typedef __attribute__((ext_vector_type(4))) float f32x4;

__device__ __forceinline__ float silu_f(float x) { return x / (1.f + __expf(-x)); }
__device__ __forceinline__ float softplus_f(float x) {
    return fmaxf(x, 0.f) + log1pf(__expf(-fabsf(x)));
}

// async 16B global->LDS (lds dest = wave-uniform base + lane*16)
#define GLOAD16(g, l)                                                          \
    __builtin_amdgcn_global_load_lds(                                          \
        (const __attribute__((address_space(1))) unsigned int*)(g),            \
        (__attribute__((address_space(3))) unsigned int*)(l), 16, 0, 0)

// ============ bf16 MFMA GEMM: C[M,N] = A[M,K] * Bt[N,K]^T (m97 structure) ====
// 128x128 tile, 256 thr = 4 waves (2x2 of 64x64), BK=32, 16x16x32 MFMA.
// Requires: M%128==0 (grid.y), N%128==0 (grid.x), K%32==0.
__global__ __launch_bounds__(256)
void gemm_bf16_bt(const __hip_bfloat16* __restrict__ A,
                  const __hip_bfloat16* __restrict__ Bt,
                  float* __restrict__ C, int N, int K)
{
    __shared__ __hip_bfloat16 As[128 * 32];
    __shared__ __hip_bfloat16 Bs[128 * 32];
    const int t    = threadIdx.x;
    const int wave = t >> 6;
    const int lane = t & 63;
    const int m0 = blockIdx.y * 128, n0 = blockIdx.x * 128;
    const int wm = (wave >> 1) * 64, wn = (wave & 1) * 64;
    const int l  = lane & 15, kq = lane >> 4;

    // staging map: chunk q in [0,512): row q>>2, 16B piece (q&3). q = t, t+256.
    const int arow = t >> 2;             // 0..63
    const int aoff = (t & 3) << 3;       // element offset 0,8,16,24
    const __hip_bfloat16* gA = A  + (size_t)(m0 + arow) * K + aoff;
    const __hip_bfloat16* gB = Bt + (size_t)(n0 + arow) * K + aoff;
    char* ldsA0 = (char*)As + wave * 1024;
    char* ldsA1 = (char*)As + 4096 + wave * 1024;
    char* ldsB0 = (char*)Bs + wave * 1024;
    char* ldsB1 = (char*)Bs + 4096 + wave * 1024;
    const size_t rstep = (size_t)64 * K;

    f32x4 acc[4][4] = {};

    for (int k0 = 0; k0 < K; k0 += 32) {
        __syncthreads();
        GLOAD16(gA + k0,         ldsA0);
        GLOAD16(gA + rstep + k0, ldsA1);
        GLOAD16(gB + k0,         ldsB0);
        GLOAD16(gB + rstep + k0, ldsB1);
        __syncthreads();

        short8 af[4], bf[4];
        #pragma unroll
        for (int i = 0; i < 4; ++i)
            af[i] = *(const short8*)(As + (wm + i * 16 + l) * 32 + kq * 8);
        #pragma unroll
        for (int j = 0; j < 4; ++j)
            bf[j] = *(const short8*)(Bs + (wn + j * 16 + l) * 32 + kq * 8);
        #pragma unroll
        for (int i = 0; i < 4; ++i)
            #pragma unroll
            for (int j = 0; j < 4; ++j)
                acc[i][j] = __builtin_amdgcn_mfma_f32_16x16x32_bf16(
                    af[i], bf[j], acc[i][j], 0, 0, 0);
    }

    // C/D layout: col = lane&15, row = (lane>>4)*4 + reg  [m89-verified]
    #pragma unroll
    for (int i = 0; i < 4; ++i)
        #pragma unroll
        for (int j = 0; j < 4; ++j)
            #pragma unroll
            for (int r = 0; r < 4; ++r) {
                int row = m0 + wm + i * 16 + kq * 4 + r;
                int col = n0 + wn + j * 16 + l;
                C[(size_t)row * N + col] = acc[i][j][r];
            }
}

// ============ elementwise cast fp32 -> bf16 (4 elems/thread) ============
__global__ __launch_bounds__(256)
void cast_bf16(const float* __restrict__ in, __hip_bfloat16* __restrict__ outp)
{
    int i = blockIdx.x * 256 + threadIdx.x;
    float4 v = ((const float4*)in)[i];
    union { ushort4 u; __hip_bfloat16 h[4]; } p;
    p.h[0] = __float2bfloat16(v.x);
    p.h[1] = __float2bfloat16(v.y);
    p.h[2] = __float2bfloat16(v.z);
    p.h[3] = __float2bfloat16(v.w);
    ((ushort4*)outp)[i] = p.u;
}

// ============ transpose + cast: W[R,C] fp32 -> Wt[C,R] bf16 ============
// 32x32 LDS tile, block 256 = (32,8). R%32==0, C%32==0.
__global__ __launch_bounds__(256)
void transpose_cast(const float* __restrict__ W, __hip_bfloat16* __restrict__ Wt,
                    int R, int C)
{
    __shared__ float tile[32][33];
    int c0 = blockIdx.x * 32, r0 = blockIdx.y * 32;
    int tx = threadIdx.x & 31, ty = threadIdx.x >> 5;
    #pragma unroll
    for (int i = 0; i < 32; i += 8)
        tile[ty + i][tx] = W[(size_t)(r0 + ty + i) * C + c0 + tx];
    __syncthreads();
    #pragma unroll
    for (int i = 0; i < 32; i += 8)
        Wt[(size_t)(c0 + ty + i) * R + r0 + tx] = __float2bfloat16(tile[tx][ty + i]);
}

// ---------------- generic fp32 tiled GEMM (kept for small/fallback GEMMs) ----
__global__ __launch_bounds__(256)
void gemm_f32(const float* __restrict__ A, const float* __restrict__ B,
              float* __restrict__ C, const float* __restrict__ bias,
              int N, int K, int lda, int ldb, int ldc, int epilogue)
{
    __shared__ float As[16][64];
    __shared__ float Bs[16][64];
    const int tid = threadIdx.x;
    const int m0 = blockIdx.y * 64;
    const int n0 = blockIdx.x * 64;
    const int tx = tid & 15, ty = tid >> 4;
    const int a_row = tid >> 2;
    const int a_k4  = (tid & 3) << 2;
    const int b_k   = tid >> 4;
    const int b_n4  = (tid & 15) << 2;
    const bool full_n = (n0 + 64) <= N;

    float acc[4][4] = {};

    for (int k0 = 0; k0 < K; k0 += 16) {
        float4 av = *(const float4*)(A + (size_t)(m0 + a_row) * lda + (k0 + a_k4));
        As[a_k4 + 0][a_row] = av.x;
        As[a_k4 + 1][a_row] = av.y;
        As[a_k4 + 2][a_row] = av.z;
        As[a_k4 + 3][a_row] = av.w;
        if (full_n) {
            *(float4*)&Bs[b_k][b_n4] =
                *(const float4*)(B + (size_t)(k0 + b_k) * ldb + (n0 + b_n4));
        } else {
            #pragma unroll
            for (int j = 0; j < 4; ++j) {
                int col = n0 + b_n4 + j;
                Bs[b_k][b_n4 + j] = (col < N) ? B[(size_t)(k0 + b_k) * ldb + col] : 0.f;
            }
        }
        __syncthreads();
        #pragma unroll
        for (int kk = 0; kk < 16; ++kk) {
            float a[4], bb[4];
            #pragma unroll
            for (int i = 0; i < 4; ++i) a[i]  = As[kk][ty * 4 + i];
            #pragma unroll
            for (int j = 0; j < 4; ++j) bb[j] = Bs[kk][tx * 4 + j];
            #pragma unroll
            for (int i = 0; i < 4; ++i)
                #pragma unroll
                for (int j = 0; j < 4; ++j)
                    acc[i][j] = fmaf(a[i], bb[j], acc[i][j]);
        }
        __syncthreads();
    }

    #pragma unroll
    for (int i = 0; i < 4; ++i) {
        size_t row = (size_t)(m0 + ty * 4 + i);
        #pragma unroll
        for (int j = 0; j < 4; ++j) {
            int col = n0 + tx * 4 + j;
            if (full_n || col < N) {
                float v = acc[i][j];
                if (epilogue == 1) v = softplus_f(v + bias[col]);
                C[row * ldc + col] = v;
            }
        }
    }
}

// ---------------- depthwise causal conv1d(4) + bias + SiLU ----------------
__global__ __launch_bounds__(256)
void conv_silu(const float* __restrict__ xz, const float* __restrict__ cw,
               const float* __restrict__ cb, float* __restrict__ uc)
{
    int idx = blockIdx.x * 256 + threadIdx.x;
    int e  = idx % D_INNER;
    int bt = idx / D_INNER;
    int t  = bt % SEQ;
    const float* base = xz + (size_t)bt * XZ_W + e;
    float w0 = cw[e * 4 + 0], w1 = cw[e * 4 + 1], w2 = cw[e * 4 + 2], w3 = cw[e * 4 + 3];
    float acc = cb[e] + w3 * base[0];
    if (t >= 1) acc = fmaf(w2, base[-(int)XZ_W], acc);
    if (t >= 2) acc = fmaf(w1, base[-2 * (int)XZ_W], acc);
    if (t >= 3) acc = fmaf(w0, base[-3 * (int)XZ_W], acc);
    uc[(size_t)bt * D_INNER + e] = silu_f(acc);
}

// ---------------- chunked parallel SSM scan ----------------
__global__ __launch_bounds__(128)
void scan_pass1(const float* __restrict__ dt, const float* __restrict__ uc,
                const float* __restrict__ smb, const float* __restrict__ A_log,
                float* __restrict__ Pbuf, float* __restrict__ Hend)
{
    const int tid = threadIdx.x;
    const int n   = tid & 15;
    const int eg  = blockIdx.x % (D_INNER / 8);
    const int c   = (blockIdx.x / (D_INNER / 8)) % CH;
    const int b   = blockIdx.x / ((D_INNER / 8) * CH);
    const int e   = eg * 8 + (tid >> 4);

    const float Av = -__expf(A_log[e * D_STATE + n]);
    float h = 0.f, P = 1.f;
    const size_t base = (size_t)b * SEQ + (size_t)c * CT;

    for (int t = 0; t < CT; ++t) {
        size_t r = base + t;
        float dt_v = dt[r * D_INNER + e];
        float u_v  = uc[r * D_INNER + e];
        float Bv   = smb[r * SSM_W + DT_RANK + n];
        float dA   = __expf(dt_v * Av);
        h = fmaf(dA, h, dt_v * Bv * u_v);
        P *= dA;
    }
    size_t i = (size_t)(b * D_INNER + e) * D_STATE + n;
    Pbuf[(size_t)c * NREC + i] = P;
    Hend[(size_t)c * NREC + i] = h;
}

__global__ __launch_bounds__(256)
void scan_pass2(float* __restrict__ Pbuf, float* __restrict__ Hend)
{
    size_t i = (size_t)blockIdx.x * 256 + threadIdx.x;
    float H = 0.f;
    for (int c = 0; c < CH; ++c) {
        size_t o = (size_t)c * NREC + i;
        float P  = Pbuf[o];
        float he = Hend[o];
        Pbuf[o] = H;
        H = fmaf(P, H, he);
    }
}

// Pass 3: bf16_out!=0 -> write y as bf16 to yout; else fp32.
// (fp32 fallback may alias dt: all lanes read dt[r,e] before lane 0 stores.)
__global__ __launch_bounds__(128)
void scan_pass3(const float* dt, const float* __restrict__ uc,
                const float* __restrict__ smb, const float* __restrict__ xz,
                const float* __restrict__ A_log, const float* __restrict__ Dp,
                const float* __restrict__ Hstart, void* yout, int bf16_out)
{
    const int tid = threadIdx.x;
    const int n   = tid & 15;
    const int eg  = blockIdx.x % (D_INNER / 8);
    const int c   = (blockIdx.x / (D_INNER / 8)) % CH;
    const int b   = blockIdx.x / ((D_INNER / 8) * CH);
    const int e   = eg * 8 + (tid >> 4);

    const float Av = -__expf(A_log[e * D_STATE + n]);
    const float Dv = Dp[e];
    size_t i = (size_t)(b * D_INNER + e) * D_STATE + n;
    float h = Hstart[(size_t)c * NREC + i];
    const size_t base = (size_t)b * SEQ + (size_t)c * CT;

    for (int t = 0; t < CT; ++t) {
        size_t r = base + t;
        float dt_v = dt[r * D_INNER + e];
        float u_v  = uc[r * D_INNER + e];
        float Bv   = smb[r * SSM_W + DT_RANK + n];
        float Cv   = smb[r * SSM_W + DT_RANK + D_STATE + n];
        float dA   = __expf(dt_v * Av);
        h = fmaf(dA, h, dt_v * Bv * u_v);
        float p = h * Cv;
        p += __shfl_xor(p, 8, 16);
        p += __shfl_xor(p, 4, 16);
        p += __shfl_xor(p, 2, 16);
        p += __shfl_xor(p, 1, 16);
        if (n == 0) {
            float res = xz[r * XZ_W + D_INNER + e];
            float y = fmaf(u_v, Dv, p) * silu_f(res);
            if (bf16_out) ((__hip_bfloat16*)yout)[r * D_INNER + e] = __float2bfloat16(y);
            else          ((float*)yout)[r * D_INNER + e] = y;
        }
    }
}

extern "C" void kernel_launch(void* const* d_in, const int* in_sizes, int n_in,
                              void* d_out, int out_size, void* d_ws, size_t ws_size,
                              hipStream_t stream)
{
    const float* x      = (const float*)d_in[0];
    const float* W_in   = (const float*)d_in[1];
    const float* conv_w = (const float*)d_in[2];
    const float* conv_b = (const float*)d_in[3];
    const float* W_x    = (const float*)d_in[4];
    const float* W_dt   = (const float*)d_in[5];
    const float* b_dt   = (const float*)d_in[6];
    const float* A_log  = (const float*)d_in[7];
    const float* Dp     = (const float*)d_in[8];
    const float* W_out  = (const float*)d_in[9];
    float* out = (float*)d_out;

    // ws layout (bytes):
    //   xz  @ 0          : 50,331,648  fp32 [4096,3072]
    //   uc  @ 50331648   : 25,165,824  fp32 [4096,1536]   (wint aliases base pre-conv)
    //   smb @ 75497472   :  1,310,720  fp32 [4096,80]
    //   dtb @ 76808192   : 25,165,824  fp32 [4096,1536]   (xb aliases base pre-GEMM4;
    //                                                      wott aliases base post-pass3)
    //   yb  @ 101974016  : 12,582,912  bf16 [4096,1536]
    //   total fast path: 114,556,928
    char*  ws  = (char*)d_ws;
    float* xz  = (float*)(ws);
    float* uc  = (float*)(ws + 50331648);
    float* smb = (float*)(ws + 75497472);
    float* dtb = (float*)(ws + 76808192);
    const bool fast = ws_size >= (size_t)114556928;

    // chunk-state buffers in d_out (dead until final GEMM): 2 x 6,291,456 B
    float* Pbuf = out;
    float* Hend = out + (size_t)CH * NREC;

    if (fast) {
        __hip_bfloat16* yb   = (__hip_bfloat16*)(ws + 101974016);
        __hip_bfloat16* xb   = (__hip_bfloat16*)dtb;   // dead before GEMM4 writes dtb
        __hip_bfloat16* wint = (__hip_bfloat16*)uc;    // dead before conv writes uc
        __hip_bfloat16* wott = (__hip_bfloat16*)dtb;   // written after pass3 (dtb dead)

        // casts / transposes for GEMM1
        cast_bf16<<<(BL * D_MODEL / 4) / 256, 256, 0, stream>>>(x, xb);
        transpose_cast<<<dim3(XZ_W / 32, D_MODEL / 32), 256, 0, stream>>>(
            W_in, wint, D_MODEL, XZ_W);

        // 1) xz = x @ W_in   (bf16 MFMA)  [4096,3072] K=768
        gemm_bf16_bt<<<dim3(XZ_W / 128, BL / 128), 256, 0, stream>>>(
            xb, wint, xz, XZ_W, D_MODEL);

        // 2) conv + SiLU -> uc
        conv_silu<<<(BL * D_INNER) / 256, 256, 0, stream>>>(xz, conv_w, conv_b, uc);

        // 3) ssm = uc @ W_x   [4096,80] K=1536 (fp32)
        gemm_f32<<<dim3(2, BL / 64), 256, 0, stream>>>(
            uc, W_x, smb, nullptr, SSM_W, D_INNER, D_INNER, SSM_W, SSM_W, 0);

        // 4) dt = softplus(ssm[:,:48] @ W_dt + b_dt)  [4096,1536] K=48 (fp32)
        gemm_f32<<<dim3(D_INNER / 64, BL / 64), 256, 0, stream>>>(
            smb, W_dt, dtb, b_dt, D_INNER, DT_RANK, SSM_W, D_INNER, D_INNER, 1);

        // 5) chunked scan -> yb (bf16)
        scan_pass1<<<BATCH * CH * (D_INNER / 8), 128, 0, stream>>>(
            dtb, uc, smb, A_log, Pbuf, Hend);
        scan_pass2<<<NREC / 256, 256, 0, stream>>>(Pbuf, Hend);
        scan_pass3<<<BATCH * CH * (D_INNER / 8), 128, 0, stream>>>(
            dtb, uc, smb, xz, A_log, Dp, Pbuf, (void*)yb, 1);

        // 6) out = y @ W_out  (bf16 MFMA)  [4096,768] K=1536
        transpose_cast<<<dim3(D_MODEL / 32, D_INNER / 32), 256, 0, stream>>>(
            W_out, wott, D_INNER, D_MODEL);
        gemm_bf16_bt<<<dim3(D_MODEL / 128, BL / 128), 256, 0, stream>>>(
            yb, wott, out, D_MODEL, D_INNER);
    } else {
        // fp32 fallback (round-2 path)
        float* yf = dtb;  // alias (safe per scan_pass3 note)
        gemm_f32<<<dim3(XZ_W / 64, BL / 64), 256, 0, stream>>>(
            x, W_in, xz, nullptr, XZ_W, D_MODEL, D_MODEL, XZ_W, XZ_W, 0);
        conv_silu<<<(BL * D_INNER) / 256, 256, 0, stream>>>(xz, conv_w, conv_b, uc);
        gemm_f32<<<dim3(2, BL / 64), 256, 0, stream>>>(
            uc, W_x, smb, nullptr, SSM_W, D_INNER, D_INNER, SSM_W, SSM_W, 0);
        gemm_f32<<<dim3(D_INNER / 64, BL / 64), 256, 0, stream>>>(
            smb, W_dt, dtb, b_dt, D_INNER, DT_RANK, SSM_W, D_INNER, D_INNER, 1);
        scan_pass1<<<BATCH * CH * (D_INNER / 8), 128, 0, stream>>>(
            dtb, uc, smb, A_log, Pbuf, Hend);
        scan_pass2<<<NREC / 256, 256, 0, stream>>>(Pbuf, Hend);
        scan_pass3<<<BATCH * CH * (D_INNER / 8), 128, 0, stream>>>(
            dtb, uc, smb, xz, A_log, Dp, Pbuf, (void*)yf, 0);
        gemm_f32<<<dim3(D_MODEL / 64, BL / 64), 256, 0, stream>>>(
            yf, W_out, out, nullptr, D_MODEL, D_INNER, D_INNER, D_MODEL, D_MODEL, 0);
    }
}

// Round 4
// 431.207 us; speedup vs baseline: 4.9229x; 1.3708x over previous
//
#include <hip/hip_runtime.h>
#include <hip/hip_bf16.h>
#include <math.h>

#define D_MODEL 768
#define D_STATE 16
#define D_CONV  4
#define D_INNER 1536
#define DT_RANK 48
#define BATCH   2
#define SEQ     2048
#define BL      (BATCH*SEQ)          // 4096 rows
#define XZ_W    (2*D_INNER)          // 3072
#define SSM_W   (DT_RANK + 2*D_STATE) // 80

#define CH      32                   // time chunks
#define CT      (SEQ/CH)             // 64 steps per chunk
#define NREC    (BATCH*D_INNER*D_STATE) // 49152 independent recurrences
#define EG      (D_INNER/128)        // 12 channel-groups of 128 per (b,c)

typedef __attribute__((ext_vector_type(8))) short short8;   // 8 bf16 (4 VGPRs)
typedef __attribute__((ext_vector_type(4))) float f32x4;

__device__ __forceinline__ float silu_f(float x) { return x / (1.f + __expf(-x)); }
__device__ __forceinline__ float softplus_f(float x) {
    return fmaxf(x, 0.f) + log1pf(__expf(-fabsf(x)));
}

// async 16B global->LDS (lds dest = wave-uniform base + lane*16)
#define GLOAD16(g, l)                                                          \
    __builtin_amdgcn_global_load_lds(                                          \
        (const __attribute__((address_space(1))) unsigned int*)(g),            \
        (__attribute__((address_space(3))) unsigned int*)(l), 16, 0, 0)

// ============ bf16 MFMA GEMM: C[M,N] = A[M,K] * Bt[N,K]^T (m97 structure) ====
__global__ __launch_bounds__(256)
void gemm_bf16_bt(const __hip_bfloat16* __restrict__ A,
                  const __hip_bfloat16* __restrict__ Bt,
                  float* __restrict__ C, int N, int K)
{
    __shared__ __hip_bfloat16 As[128 * 32];
    __shared__ __hip_bfloat16 Bs[128 * 32];
    const int t    = threadIdx.x;
    const int wave = t >> 6;
    const int lane = t & 63;
    const int m0 = blockIdx.y * 128, n0 = blockIdx.x * 128;
    const int wm = (wave >> 1) * 64, wn = (wave & 1) * 64;
    const int l  = lane & 15, kq = lane >> 4;

    const int arow = t >> 2;
    const int aoff = (t & 3) << 3;
    const __hip_bfloat16* gA = A  + (size_t)(m0 + arow) * K + aoff;
    const __hip_bfloat16* gB = Bt + (size_t)(n0 + arow) * K + aoff;
    char* ldsA0 = (char*)As + wave * 1024;
    char* ldsA1 = (char*)As + 4096 + wave * 1024;
    char* ldsB0 = (char*)Bs + wave * 1024;
    char* ldsB1 = (char*)Bs + 4096 + wave * 1024;
    const size_t rstep = (size_t)64 * K;

    f32x4 acc[4][4] = {};

    for (int k0 = 0; k0 < K; k0 += 32) {
        __syncthreads();
        GLOAD16(gA + k0,         ldsA0);
        GLOAD16(gA + rstep + k0, ldsA1);
        GLOAD16(gB + k0,         ldsB0);
        GLOAD16(gB + rstep + k0, ldsB1);
        __syncthreads();

        short8 af[4], bf[4];
        #pragma unroll
        for (int i = 0; i < 4; ++i)
            af[i] = *(const short8*)(As + (wm + i * 16 + l) * 32 + kq * 8);
        #pragma unroll
        for (int j = 0; j < 4; ++j)
            bf[j] = *(const short8*)(Bs + (wn + j * 16 + l) * 32 + kq * 8);
        #pragma unroll
        for (int i = 0; i < 4; ++i)
            #pragma unroll
            for (int j = 0; j < 4; ++j)
                acc[i][j] = __builtin_amdgcn_mfma_f32_16x16x32_bf16(
                    af[i], bf[j], acc[i][j], 0, 0, 0);
    }

    #pragma unroll
    for (int i = 0; i < 4; ++i)
        #pragma unroll
        for (int j = 0; j < 4; ++j)
            #pragma unroll
            for (int r = 0; r < 4; ++r) {
                int row = m0 + wm + i * 16 + kq * 4 + r;
                int col = n0 + wn + j * 16 + l;
                C[(size_t)row * N + col] = acc[i][j][r];
            }
}

// ============ elementwise cast fp32 -> bf16 ============
__global__ __launch_bounds__(256)
void cast_bf16(const float* __restrict__ in, __hip_bfloat16* __restrict__ outp)
{
    int i = blockIdx.x * 256 + threadIdx.x;
    float4 v = ((const float4*)in)[i];
    union { ushort4 u; __hip_bfloat16 h[4]; } p;
    p.h[0] = __float2bfloat16(v.x);
    p.h[1] = __float2bfloat16(v.y);
    p.h[2] = __float2bfloat16(v.z);
    p.h[3] = __float2bfloat16(v.w);
    ((ushort4*)outp)[i] = p.u;
}

// ============ transpose + cast: W[R,C] fp32 -> Wt[C,R] bf16 ============
__global__ __launch_bounds__(256)
void transpose_cast(const float* __restrict__ W, __hip_bfloat16* __restrict__ Wt,
                    int R, int C)
{
    __shared__ float tile[32][33];
    int c0 = blockIdx.x * 32, r0 = blockIdx.y * 32;
    int tx = threadIdx.x & 31, ty = threadIdx.x >> 5;
    #pragma unroll
    for (int i = 0; i < 32; i += 8)
        tile[ty + i][tx] = W[(size_t)(r0 + ty + i) * C + c0 + tx];
    __syncthreads();
    #pragma unroll
    for (int i = 0; i < 32; i += 8)
        Wt[(size_t)(c0 + ty + i) * R + r0 + tx] = __float2bfloat16(tile[tx][ty + i]);
}

// ---------------- generic fp32 tiled GEMM ----------------
__global__ __launch_bounds__(256)
void gemm_f32(const float* __restrict__ A, const float* __restrict__ B,
              float* __restrict__ C, const float* __restrict__ bias,
              int N, int K, int lda, int ldb, int ldc, int epilogue)
{
    __shared__ float As[16][64];
    __shared__ float Bs[16][64];
    const int tid = threadIdx.x;
    const int m0 = blockIdx.y * 64;
    const int n0 = blockIdx.x * 64;
    const int tx = tid & 15, ty = tid >> 4;
    const int a_row = tid >> 2;
    const int a_k4  = (tid & 3) << 2;
    const int b_k   = tid >> 4;
    const int b_n4  = (tid & 15) << 2;
    const bool full_n = (n0 + 64) <= N;

    float acc[4][4] = {};

    for (int k0 = 0; k0 < K; k0 += 16) {
        float4 av = *(const float4*)(A + (size_t)(m0 + a_row) * lda + (k0 + a_k4));
        As[a_k4 + 0][a_row] = av.x;
        As[a_k4 + 1][a_row] = av.y;
        As[a_k4 + 2][a_row] = av.z;
        As[a_k4 + 3][a_row] = av.w;
        if (full_n) {
            *(float4*)&Bs[b_k][b_n4] =
                *(const float4*)(B + (size_t)(k0 + b_k) * ldb + (n0 + b_n4));
        } else {
            #pragma unroll
            for (int j = 0; j < 4; ++j) {
                int col = n0 + b_n4 + j;
                Bs[b_k][b_n4 + j] = (col < N) ? B[(size_t)(k0 + b_k) * ldb + col] : 0.f;
            }
        }
        __syncthreads();
        #pragma unroll
        for (int kk = 0; kk < 16; ++kk) {
            float a[4], bb[4];
            #pragma unroll
            for (int i = 0; i < 4; ++i) a[i]  = As[kk][ty * 4 + i];
            #pragma unroll
            for (int j = 0; j < 4; ++j) bb[j] = Bs[kk][tx * 4 + j];
            #pragma unroll
            for (int i = 0; i < 4; ++i)
                #pragma unroll
                for (int j = 0; j < 4; ++j)
                    acc[i][j] = fmaf(a[i], bb[j], acc[i][j]);
        }
        __syncthreads();
    }

    #pragma unroll
    for (int i = 0; i < 4; ++i) {
        size_t row = (size_t)(m0 + ty * 4 + i);
        #pragma unroll
        for (int j = 0; j < 4; ++j) {
            int col = n0 + tx * 4 + j;
            if (full_n || col < N) {
                float v = acc[i][j];
                if (epilogue == 1) v = softplus_f(v + bias[col]);
                C[row * ldc + col] = v;
            }
        }
    }
}

// ---------------- depthwise causal conv1d(4) + bias + SiLU ----------------
__global__ __launch_bounds__(256)
void conv_silu(const float* __restrict__ xz, const float* __restrict__ cw,
               const float* __restrict__ cb, float* __restrict__ uc)
{
    int idx = blockIdx.x * 256 + threadIdx.x;
    int e  = idx % D_INNER;
    int bt = idx / D_INNER;
    int t  = bt % SEQ;
    const float* base = xz + (size_t)bt * XZ_W + e;
    float w0 = cw[e * 4 + 0], w1 = cw[e * 4 + 1], w2 = cw[e * 4 + 2], w3 = cw[e * 4 + 3];
    float acc = cb[e] + w3 * base[0];
    if (t >= 1) acc = fmaf(w2, base[-(int)XZ_W], acc);
    if (t >= 2) acc = fmaf(w1, base[-2 * (int)XZ_W], acc);
    if (t >= 3) acc = fmaf(w0, base[-3 * (int)XZ_W], acc);
    uc[(size_t)bt * D_INNER + e] = silu_f(acc);
}

// ============ chunked parallel SSM scan, v2 (thread per channel-half) ========
// Mapping: block = 256 thr covers 128 channels x 2 halves of one (b, chunk).
//   e = eg*128 + (tid>>1), half = tid&1, states n = half*8 .. half*8+7.
// dt/uc/res loads are coalesced (lane pairs share an address -> 128 B/wave).
// B (and C in pass3) staged per-chunk in LDS; reads are 2-address broadcasts.

// Pass 1: local scan h0=0 -> Hend; decay P = exp(Av * sum(dt)).
__global__ __launch_bounds__(256)
void scan_pass1(const float* __restrict__ dt, const float* __restrict__ uc,
                const float* __restrict__ smb, const float* __restrict__ A_log,
                float* __restrict__ Pbuf, float* __restrict__ Hend)
{
    __shared__ float Bs[CT][16];      // 4 KB
    const int tid  = threadIdx.x;
    const int half = tid & 1;
    const int eg   = blockIdx.x % EG;
    const int c    = (blockIdx.x / EG) % CH;
    const int b    = blockIdx.x / (EG * CH);
    const int e    = eg * 128 + (tid >> 1);
    const size_t base = (size_t)b * SEQ + (size_t)c * CT;

    for (int idx = tid; idx < CT * 16; idx += 256) {
        int tr = idx >> 4, col = idx & 15;
        Bs[tr][col] = smb[(base + tr) * SSM_W + DT_RANK + col];
    }
    __syncthreads();

    float Av[8];
    {
        float4 a0 = *(const float4*)&A_log[e * D_STATE + half * 8];
        float4 a1 = *(const float4*)&A_log[e * D_STATE + half * 8 + 4];
        Av[0] = -__expf(a0.x); Av[1] = -__expf(a0.y);
        Av[2] = -__expf(a0.z); Av[3] = -__expf(a0.w);
        Av[4] = -__expf(a1.x); Av[5] = -__expf(a1.y);
        Av[6] = -__expf(a1.z); Av[7] = -__expf(a1.w);
    }

    float h[8] = {};
    float sdt = 0.f;

    #pragma unroll 4
    for (int t = 0; t < CT; ++t) {
        size_t r = base + t;
        float dt_v = dt[r * D_INNER + e];
        float u_v  = uc[r * D_INNER + e];
        sdt += dt_v;
        float du = dt_v * u_v;
        float bl[8];
        *(float4*)&bl[0] = *(const float4*)&Bs[t][half * 8];
        *(float4*)&bl[4] = *(const float4*)&Bs[t][half * 8 + 4];
        #pragma unroll
        for (int n = 0; n < 8; ++n)
            h[n] = fmaf(__expf(dt_v * Av[n]), h[n], du * bl[n]);
    }

    float P[8];
    #pragma unroll
    for (int n = 0; n < 8; ++n) P[n] = __expf(Av[n] * sdt);

    size_t i = (size_t)c * NREC + (size_t)(b * D_INNER + e) * D_STATE + half * 8;
    *(float4*)&Pbuf[i]     = *(float4*)&P[0];
    *(float4*)&Pbuf[i + 4] = *(float4*)&P[4];
    *(float4*)&Hend[i]     = *(float4*)&h[0];
    *(float4*)&Hend[i + 4] = *(float4*)&h[4];
}

// Pass 2: sequential combine over chunks; one thread per (b,e,n).
__global__ __launch_bounds__(256)
void scan_pass2(float* __restrict__ Pbuf, float* __restrict__ Hend)
{
    size_t i = (size_t)blockIdx.x * 256 + threadIdx.x;
    float H = 0.f;
    for (int c = 0; c < CH; ++c) {
        size_t o = (size_t)c * NREC + i;
        float P  = Pbuf[o];
        float he = Hend[o];
        Pbuf[o] = H;
        H = fmaf(P, H, he);
    }
}

// Pass 3: recompute with true start state; emit y (bf16 or fp32).
// fp32 fallback may alias dt/yout: each (r,e) touched only by one lane pair,
// and both lanes read dt before the half==0 lane stores (program order). Safe.
__global__ __launch_bounds__(256)
void scan_pass3(const float* dt, const float* __restrict__ uc,
                const float* __restrict__ smb, const float* __restrict__ xz,
                const float* __restrict__ A_log, const float* __restrict__ Dp,
                const float* __restrict__ Hstart, void* yout, int bf16_out)
{
    __shared__ float BCs[CT][32];     // 8 KB: [t][0..15]=B, [t][16..31]=C
    const int tid  = threadIdx.x;
    const int half = tid & 1;
    const int eg   = blockIdx.x % EG;
    const int c    = (blockIdx.x / EG) % CH;
    const int b    = blockIdx.x / (EG * CH);
    const int e    = eg * 128 + (tid >> 1);
    const size_t base = (size_t)b * SEQ + (size_t)c * CT;

    for (int idx = tid; idx < CT * 32; idx += 256) {
        int tr = idx >> 5, col = idx & 31;
        BCs[tr][col] = smb[(base + tr) * SSM_W + DT_RANK + col];
    }
    __syncthreads();

    float Av[8];
    {
        float4 a0 = *(const float4*)&A_log[e * D_STATE + half * 8];
        float4 a1 = *(const float4*)&A_log[e * D_STATE + half * 8 + 4];
        Av[0] = -__expf(a0.x); Av[1] = -__expf(a0.y);
        Av[2] = -__expf(a0.z); Av[3] = -__expf(a0.w);
        Av[4] = -__expf(a1.x); Av[5] = -__expf(a1.y);
        Av[6] = -__expf(a1.z); Av[7] = -__expf(a1.w);
    }
    const float Dv = Dp[e];

    float h[8];
    {
        const float* hp = Hstart + (size_t)c * NREC
                        + (size_t)(b * D_INNER + e) * D_STATE + half * 8;
        *(float4*)&h[0] = *(const float4*)hp;
        *(float4*)&h[4] = *(const float4*)(hp + 4);
    }

    #pragma unroll 4
    for (int t = 0; t < CT; ++t) {
        size_t r = base + t;
        float dt_v = dt[r * D_INNER + e];
        float u_v  = uc[r * D_INNER + e];
        float res  = xz[r * XZ_W + D_INNER + e];
        float bl[8], cl[8];
        *(float4*)&bl[0] = *(const float4*)&BCs[t][half * 8];
        *(float4*)&bl[4] = *(const float4*)&BCs[t][half * 8 + 4];
        *(float4*)&cl[0] = *(const float4*)&BCs[t][16 + half * 8];
        *(float4*)&cl[4] = *(const float4*)&BCs[t][16 + half * 8 + 4];
        float du = dt_v * u_v;
        float p = 0.f;
        #pragma unroll
        for (int n = 0; n < 8; ++n) {
            h[n] = fmaf(__expf(dt_v * Av[n]), h[n], du * bl[n]);
            p = fmaf(h[n], cl[n], p);
        }
        p += __shfl_xor(p, 1);
        if (half == 0) {
            float y = fmaf(u_v, Dv, p) * silu_f(res);
            if (bf16_out) ((__hip_bfloat16*)yout)[r * D_INNER + e] = __float2bfloat16(y);
            else          ((float*)yout)[r * D_INNER + e] = y;
        }
    }
}

extern "C" void kernel_launch(void* const* d_in, const int* in_sizes, int n_in,
                              void* d_out, int out_size, void* d_ws, size_t ws_size,
                              hipStream_t stream)
{
    const float* x      = (const float*)d_in[0];
    const float* W_in   = (const float*)d_in[1];
    const float* conv_w = (const float*)d_in[2];
    const float* conv_b = (const float*)d_in[3];
    const float* W_x    = (const float*)d_in[4];
    const float* W_dt   = (const float*)d_in[5];
    const float* b_dt   = (const float*)d_in[6];
    const float* A_log  = (const float*)d_in[7];
    const float* Dp     = (const float*)d_in[8];
    const float* W_out  = (const float*)d_in[9];
    float* out = (float*)d_out;

    char*  ws  = (char*)d_ws;
    float* xz  = (float*)(ws);
    float* uc  = (float*)(ws + 50331648);
    float* smb = (float*)(ws + 75497472);
    float* dtb = (float*)(ws + 76808192);
    const bool fast = ws_size >= (size_t)114556928;

    float* Pbuf = out;
    float* Hend = out + (size_t)CH * NREC;

    const int scan_grid = BATCH * CH * EG;   // 768 blocks

    if (fast) {
        __hip_bfloat16* yb   = (__hip_bfloat16*)(ws + 101974016);
        __hip_bfloat16* xb   = (__hip_bfloat16*)dtb;
        __hip_bfloat16* wint = (__hip_bfloat16*)uc;
        __hip_bfloat16* wott = (__hip_bfloat16*)dtb;

        cast_bf16<<<(BL * D_MODEL / 4) / 256, 256, 0, stream>>>(x, xb);
        transpose_cast<<<dim3(XZ_W / 32, D_MODEL / 32), 256, 0, stream>>>(
            W_in, wint, D_MODEL, XZ_W);

        gemm_bf16_bt<<<dim3(XZ_W / 128, BL / 128), 256, 0, stream>>>(
            xb, wint, xz, XZ_W, D_MODEL);

        conv_silu<<<(BL * D_INNER) / 256, 256, 0, stream>>>(xz, conv_w, conv_b, uc);

        gemm_f32<<<dim3(2, BL / 64), 256, 0, stream>>>(
            uc, W_x, smb, nullptr, SSM_W, D_INNER, D_INNER, SSM_W, SSM_W, 0);

        gemm_f32<<<dim3(D_INNER / 64, BL / 64), 256, 0, stream>>>(
            smb, W_dt, dtb, b_dt, D_INNER, DT_RANK, SSM_W, D_INNER, D_INNER, 1);

        scan_pass1<<<scan_grid, 256, 0, stream>>>(dtb, uc, smb, A_log, Pbuf, Hend);
        scan_pass2<<<NREC / 256, 256, 0, stream>>>(Pbuf, Hend);
        scan_pass3<<<scan_grid, 256, 0, stream>>>(
            dtb, uc, smb, xz, A_log, Dp, Pbuf, (void*)yb, 1);

        transpose_cast<<<dim3(D_MODEL / 32, D_INNER / 32), 256, 0, stream>>>(
            W_out, wott, D_INNER, D_MODEL);
        gemm_bf16_bt<<<dim3(D_MODEL / 128, BL / 128), 256, 0, stream>>>(
            yb, wott, out, D_MODEL, D_INNER);
    } else {
        float* yf = dtb;
        gemm_f32<<<dim3(XZ_W / 64, BL / 64), 256, 0, stream>>>(
            x, W_in, xz, nullptr, XZ_W, D_MODEL, D_MODEL, XZ_W, XZ_W, 0);
        conv_silu<<<(BL * D_INNER) / 256, 256, 0, stream>>>(xz, conv_w, conv_b, uc);
        gemm_f32<<<dim3(2, BL / 64), 256, 0, stream>>>(
            uc, W_x, smb, nullptr, SSM_W, D_INNER, D_INNER, SSM_W, SSM_W, 0);
        gemm_f32<<<dim3(D_INNER / 64, BL / 64), 256, 0, stream>>>(
            smb, W_dt, dtb, b_dt, D_INNER, DT_RANK, SSM_W, D_INNER, D_INNER, 1);
        scan_pass1<<<scan_grid, 256, 0, stream>>>(dtb, uc, smb, A_log, Pbuf, Hend);
        scan_pass2<<<NREC / 256, 256, 0, stream>>>(Pbuf, Hend);
        scan_pass3<<<scan_grid, 256, 0, stream>>>(
            dtb, uc, smb, xz, A_log, Dp, Pbuf, (void*)yf, 0);
        gemm_f32<<<dim3(D_MODEL / 64, BL / 64), 256, 0, stream>>>(
            yf, W_out, out, nullptr, D_MODEL, D_INNER, D_INNER, D_MODEL, D_MODEL, 0);
    }
}

// Round 5
// 394.518 us; speedup vs baseline: 5.3807x; 1.0930x over previous
//
#include <hip/hip_runtime.h>
#include <hip/hip_bf16.h>
#include <math.h>

#define D_MODEL 768
#define D_STATE 16
#define D_CONV  4
#define D_INNER 1536
#define DT_RANK 48
#define BATCH   2
#define SEQ     2048
#define BL      (BATCH*SEQ)          // 4096 rows
#define XZ_W    (2*D_INNER)          // 3072
#define SSM_W   (DT_RANK + 2*D_STATE) // 80
#define BC_W    (2*D_STATE)          // 32
#define DTBC_LD (D_INNER + BC_W)     // 1568 (row stride of fused dt|B|C buffer)
#define DTBC_N  1664                 // 13*128 padded GEMM width

#define CH      32                   // time chunks
#define CT      (SEQ/CH)             // 64 steps per chunk
#define NREC    (BATCH*D_INNER*D_STATE) // 49152 independent recurrences
#define EG      (D_INNER/128)        // 12 channel-groups of 128 per (b,c)

typedef __attribute__((ext_vector_type(8))) short short8;   // 8 bf16 (4 VGPRs)
typedef __attribute__((ext_vector_type(4))) float f32x4;

__device__ __forceinline__ float silu_f(float x) { return x / (1.f + __expf(-x)); }
__device__ __forceinline__ float softplus_f(float x) {
    return fmaxf(x, 0.f) + log1pf(__expf(-fabsf(x)));
}

// async 16B global->LDS (lds dest = wave-uniform base + lane*16)
#define GLOAD16(g, l)                                                          \
    __builtin_amdgcn_global_load_lds(                                          \
        (const __attribute__((address_space(1))) unsigned int*)(g),            \
        (__attribute__((address_space(3))) unsigned int*)(l), 16, 0, 0)

// ============ bf16 MFMA GEMM: C = A[M,K] * Bt[N,K]^T (m97 structure) ========
// 128x128 tile, 256 thr = 4 waves (2x2 of 64x64), BK=32, 16x16x32 MFMA.
// M%128==0, N%128==0 (grid), K%32==0.
// mode 0: C0[row*ldc+col] = v
// mode 1: split u|res: col<1536 -> C0[row*1536+col], else C1[row*1536+col-1536]
// mode 2: fused dt|B|C: col<1536 -> C0[row*ldc+col]=softplus(v+bias[col]);
//         col<1568 -> plain; col>=1568 (pad) -> skip
__global__ __launch_bounds__(256)
void gemm_bf16_bt(const __hip_bfloat16* __restrict__ A,
                  const __hip_bfloat16* __restrict__ Bt,
                  float* __restrict__ C0, float* __restrict__ C1,
                  const float* __restrict__ bias,
                  int N, int K, int ldc, int mode)
{
    __shared__ __hip_bfloat16 As[128 * 32];
    __shared__ __hip_bfloat16 Bs[128 * 32];
    const int t    = threadIdx.x;
    const int wave = t >> 6;
    const int lane = t & 63;
    const int m0 = blockIdx.y * 128, n0 = blockIdx.x * 128;
    const int wm = (wave >> 1) * 64, wn = (wave & 1) * 64;
    const int l  = lane & 15, kq = lane >> 4;

    const int arow = t >> 2;
    const int aoff = (t & 3) << 3;
    const __hip_bfloat16* gA = A  + (size_t)(m0 + arow) * K + aoff;
    const __hip_bfloat16* gB = Bt + (size_t)(n0 + arow) * K + aoff;
    char* ldsA0 = (char*)As + wave * 1024;
    char* ldsA1 = (char*)As + 4096 + wave * 1024;
    char* ldsB0 = (char*)Bs + wave * 1024;
    char* ldsB1 = (char*)Bs + 4096 + wave * 1024;
    const size_t rstep = (size_t)64 * K;

    f32x4 acc[4][4] = {};

    for (int k0 = 0; k0 < K; k0 += 32) {
        __syncthreads();
        GLOAD16(gA + k0,         ldsA0);
        GLOAD16(gA + rstep + k0, ldsA1);
        GLOAD16(gB + k0,         ldsB0);
        GLOAD16(gB + rstep + k0, ldsB1);
        __syncthreads();

        short8 af[4], bf[4];
        #pragma unroll
        for (int i = 0; i < 4; ++i)
            af[i] = *(const short8*)(As + (wm + i * 16 + l) * 32 + kq * 8);
        #pragma unroll
        for (int j = 0; j < 4; ++j)
            bf[j] = *(const short8*)(Bs + (wn + j * 16 + l) * 32 + kq * 8);
        #pragma unroll
        for (int i = 0; i < 4; ++i)
            #pragma unroll
            for (int j = 0; j < 4; ++j)
                acc[i][j] = __builtin_amdgcn_mfma_f32_16x16x32_bf16(
                    af[i], bf[j], acc[i][j], 0, 0, 0);
    }

    // C/D layout: col = lane&15, row = (lane>>4)*4 + reg  [m89-verified]
    #pragma unroll
    for (int i = 0; i < 4; ++i)
        #pragma unroll
        for (int j = 0; j < 4; ++j)
            #pragma unroll
            for (int r = 0; r < 4; ++r) {
                int row = m0 + wm + i * 16 + kq * 4 + r;
                int col = n0 + wn + j * 16 + l;
                float v = acc[i][j][r];
                if (mode == 0) {
                    C0[(size_t)row * ldc + col] = v;
                } else if (mode == 1) {
                    if (col < D_INNER) C0[(size_t)row * D_INNER + col] = v;
                    else               C1[(size_t)row * D_INNER + col - D_INNER] = v;
                } else {
                    if (col < D_INNER)
                        C0[(size_t)row * ldc + col] = softplus_f(v + bias[col]);
                    else if (col < D_INNER + BC_W)
                        C0[(size_t)row * ldc + col] = v;
                }
            }
}

// ============ elementwise cast fp32 -> bf16 ============
__global__ __launch_bounds__(256)
void cast_bf16(const float* __restrict__ in, __hip_bfloat16* __restrict__ outp)
{
    int i = blockIdx.x * 256 + threadIdx.x;
    float4 v = ((const float4*)in)[i];
    union { ushort4 u; __hip_bfloat16 h[4]; } p;
    p.h[0] = __float2bfloat16(v.x);
    p.h[1] = __float2bfloat16(v.y);
    p.h[2] = __float2bfloat16(v.z);
    p.h[3] = __float2bfloat16(v.w);
    ((ushort4*)outp)[i] = p.u;
}

// ============ transpose + cast: W[R,C] (row stride lda) fp32 -> Wt[C,R] bf16 ==
__global__ __launch_bounds__(256)
void transpose_cast(const float* __restrict__ W, __hip_bfloat16* __restrict__ Wt,
                    int R, int C, int lda)
{
    __shared__ float tile[32][33];
    int c0 = blockIdx.x * 32, r0 = blockIdx.y * 32;
    int tx = threadIdx.x & 31, ty = threadIdx.x >> 5;
    #pragma unroll
    for (int i = 0; i < 32; i += 8)
        tile[ty + i][tx] = W[(size_t)(r0 + ty + i) * lda + c0 + tx];
    __syncthreads();
    #pragma unroll
    for (int i = 0; i < 32; i += 8)
        Wt[(size_t)(c0 + ty + i) * R + r0 + tx] = __float2bfloat16(tile[tx][ty + i]);
}

// ---------------- generic fp32 tiled GEMM (W_eff + fallback path) ----------
__global__ __launch_bounds__(256)
void gemm_f32(const float* __restrict__ A, const float* __restrict__ B,
              float* __restrict__ C, const float* __restrict__ bias,
              int N, int K, int lda, int ldb, int ldc, int epilogue)
{
    __shared__ float As[16][64];
    __shared__ float Bs[16][64];
    const int tid = threadIdx.x;
    const int m0 = blockIdx.y * 64;
    const int n0 = blockIdx.x * 64;
    const int tx = tid & 15, ty = tid >> 4;
    const int a_row = tid >> 2;
    const int a_k4  = (tid & 3) << 2;
    const int b_k   = tid >> 4;
    const int b_n4  = (tid & 15) << 2;
    const bool full_n = (n0 + 64) <= N;

    float acc[4][4] = {};

    for (int k0 = 0; k0 < K; k0 += 16) {
        float4 av = *(const float4*)(A + (size_t)(m0 + a_row) * lda + (k0 + a_k4));
        As[a_k4 + 0][a_row] = av.x;
        As[a_k4 + 1][a_row] = av.y;
        As[a_k4 + 2][a_row] = av.z;
        As[a_k4 + 3][a_row] = av.w;
        if (full_n) {
            *(float4*)&Bs[b_k][b_n4] =
                *(const float4*)(B + (size_t)(k0 + b_k) * ldb + (n0 + b_n4));
        } else {
            #pragma unroll
            for (int j = 0; j < 4; ++j) {
                int col = n0 + b_n4 + j;
                Bs[b_k][b_n4 + j] = (col < N) ? B[(size_t)(k0 + b_k) * ldb + col] : 0.f;
            }
        }
        __syncthreads();
        #pragma unroll
        for (int kk = 0; kk < 16; ++kk) {
            float a[4], bb[4];
            #pragma unroll
            for (int i = 0; i < 4; ++i) a[i]  = As[kk][ty * 4 + i];
            #pragma unroll
            for (int j = 0; j < 4; ++j) bb[j] = Bs[kk][tx * 4 + j];
            #pragma unroll
            for (int i = 0; i < 4; ++i)
                #pragma unroll
                for (int j = 0; j < 4; ++j)
                    acc[i][j] = fmaf(a[i], bb[j], acc[i][j]);
        }
        __syncthreads();
    }

    #pragma unroll
    for (int i = 0; i < 4; ++i) {
        size_t row = (size_t)(m0 + ty * 4 + i);
        #pragma unroll
        for (int j = 0; j < 4; ++j) {
            int col = n0 + tx * 4 + j;
            if (full_n || col < N) {
                float v = acc[i][j];
                if (epilogue == 1) v = softplus_f(v + bias[col]);
                C[row * ldc + col] = v;
            }
        }
    }
}

// ---------------- depthwise causal conv1d(4) + bias + SiLU ----------------
// in: [BL, in_ld] (u occupies cols 0..1535). Writes uc fp32; optionally ucb bf16.
__global__ __launch_bounds__(256)
void conv_silu(const float* __restrict__ in, const float* __restrict__ cw,
               const float* __restrict__ cb, float* __restrict__ uc,
               __hip_bfloat16* __restrict__ ucb, int in_ld, int write_b)
{
    int idx = blockIdx.x * 256 + threadIdx.x;
    int e  = idx % D_INNER;
    int bt = idx / D_INNER;
    int t  = bt % SEQ;
    const float* base = in + (size_t)bt * in_ld + e;
    float w0 = cw[e * 4 + 0], w1 = cw[e * 4 + 1], w2 = cw[e * 4 + 2], w3 = cw[e * 4 + 3];
    float acc = cb[e] + w3 * base[0];
    if (t >= 1) acc = fmaf(w2, base[-in_ld], acc);
    if (t >= 2) acc = fmaf(w1, base[-2 * in_ld], acc);
    if (t >= 3) acc = fmaf(w0, base[-3 * in_ld], acc);
    float v = silu_f(acc);
    uc[(size_t)bt * D_INNER + e] = v;
    if (write_b) ucb[(size_t)bt * D_INNER + e] = __float2bfloat16(v);
}

// ============ chunked parallel SSM scan (thread per channel-half) ============
// block = 256 thr = 128 channels x 2 halves of one (b, chunk).
// dt: [BL, dt_ld] col e. bc: [BL, bc_ld] cols 0..15 = B, 16..31 = C.

// Pass 1: local scan h0=0 -> Hend; decay P = exp(Av * sum(dt)).
__global__ __launch_bounds__(256)
void scan_pass1(const float* __restrict__ dt, int dt_ld,
                const float* __restrict__ uc,
                const float* __restrict__ bc, int bc_ld,
                const float* __restrict__ A_log,
                float* __restrict__ Pbuf, float* __restrict__ Hend)
{
    __shared__ float Bs[CT][16];      // 4 KB
    const int tid  = threadIdx.x;
    const int half = tid & 1;
    const int eg   = blockIdx.x % EG;
    const int c    = (blockIdx.x / EG) % CH;
    const int b    = blockIdx.x / (EG * CH);
    const int e    = eg * 128 + (tid >> 1);
    const size_t base = (size_t)b * SEQ + (size_t)c * CT;

    for (int idx = tid; idx < CT * 16; idx += 256) {
        int tr = idx >> 4, col = idx & 15;
        Bs[tr][col] = bc[(base + tr) * bc_ld + col];
    }
    __syncthreads();

    float Av[8];
    {
        float4 a0 = *(const float4*)&A_log[e * D_STATE + half * 8];
        float4 a1 = *(const float4*)&A_log[e * D_STATE + half * 8 + 4];
        Av[0] = -__expf(a0.x); Av[1] = -__expf(a0.y);
        Av[2] = -__expf(a0.z); Av[3] = -__expf(a0.w);
        Av[4] = -__expf(a1.x); Av[5] = -__expf(a1.y);
        Av[6] = -__expf(a1.z); Av[7] = -__expf(a1.w);
    }

    float h[8] = {};
    float sdt = 0.f;

    #pragma unroll 4
    for (int t = 0; t < CT; ++t) {
        size_t r = base + t;
        float dt_v = dt[r * dt_ld + e];
        float u_v  = uc[r * D_INNER + e];
        sdt += dt_v;
        float du = dt_v * u_v;
        float bl[8];
        *(float4*)&bl[0] = *(const float4*)&Bs[t][half * 8];
        *(float4*)&bl[4] = *(const float4*)&Bs[t][half * 8 + 4];
        #pragma unroll
        for (int n = 0; n < 8; ++n)
            h[n] = fmaf(__expf(dt_v * Av[n]), h[n], du * bl[n]);
    }

    float P[8];
    #pragma unroll
    for (int n = 0; n < 8; ++n) P[n] = __expf(Av[n] * sdt);

    size_t i = (size_t)c * NREC + (size_t)(b * D_INNER + e) * D_STATE + half * 8;
    *(float4*)&Pbuf[i]     = *(float4*)&P[0];
    *(float4*)&Pbuf[i + 4] = *(float4*)&P[4];
    *(float4*)&Hend[i]     = *(float4*)&h[0];
    *(float4*)&Hend[i + 4] = *(float4*)&h[4];
}

// Pass 2: sequential combine over chunks; one thread per (b,e,n).
__global__ __launch_bounds__(256)
void scan_pass2(float* __restrict__ Pbuf, float* __restrict__ Hend)
{
    size_t i = (size_t)blockIdx.x * 256 + threadIdx.x;
    float H = 0.f;
    for (int c = 0; c < CH; ++c) {
        size_t o = (size_t)c * NREC + i;
        float P  = Pbuf[o];
        float he = Hend[o];
        Pbuf[o] = H;
        H = fmaf(P, H, he);
    }
}

// Pass 3: recompute with true start state; emit y (bf16 or fp32).
// Fallback may alias dt/yout: both lanes load dt before half==0 stores. Safe.
__global__ __launch_bounds__(256)
void scan_pass3(const float* dt, int dt_ld,
                const float* __restrict__ uc,
                const float* __restrict__ bc, int bc_ld,
                const float* __restrict__ res, int res_ld,
                const float* __restrict__ A_log, const float* __restrict__ Dp,
                const float* __restrict__ Hstart, void* yout, int bf16_out)
{
    __shared__ float BCs[CT][32];     // 8 KB: [t][0..15]=B, [t][16..31]=C
    const int tid  = threadIdx.x;
    const int half = tid & 1;
    const int eg   = blockIdx.x % EG;
    const int c    = (blockIdx.x / EG) % CH;
    const int b    = blockIdx.x / (EG * CH);
    const int e    = eg * 128 + (tid >> 1);
    const size_t base = (size_t)b * SEQ + (size_t)c * CT;

    for (int idx = tid; idx < CT * 32; idx += 256) {
        int tr = idx >> 5, col = idx & 31;
        BCs[tr][col] = bc[(base + tr) * bc_ld + col];
    }
    __syncthreads();

    float Av[8];
    {
        float4 a0 = *(const float4*)&A_log[e * D_STATE + half * 8];
        float4 a1 = *(const float4*)&A_log[e * D_STATE + half * 8 + 4];
        Av[0] = -__expf(a0.x); Av[1] = -__expf(a0.y);
        Av[2] = -__expf(a0.z); Av[3] = -__expf(a0.w);
        Av[4] = -__expf(a1.x); Av[5] = -__expf(a1.y);
        Av[6] = -__expf(a1.z); Av[7] = -__expf(a1.w);
    }
    const float Dv = Dp[e];

    float h[8];
    {
        const float* hp = Hstart + (size_t)c * NREC
                        + (size_t)(b * D_INNER + e) * D_STATE + half * 8;
        *(float4*)&h[0] = *(const float4*)hp;
        *(float4*)&h[4] = *(const float4*)(hp + 4);
    }

    #pragma unroll 4
    for (int t = 0; t < CT; ++t) {
        size_t r = base + t;
        float dt_v = dt[r * dt_ld + e];
        float u_v  = uc[r * D_INNER + e];
        float rs   = res[r * res_ld + e];
        float bl[8], cl[8];
        *(float4*)&bl[0] = *(const float4*)&BCs[t][half * 8];
        *(float4*)&bl[4] = *(const float4*)&BCs[t][half * 8 + 4];
        *(float4*)&cl[0] = *(const float4*)&BCs[t][16 + half * 8];
        *(float4*)&cl[4] = *(const float4*)&BCs[t][16 + half * 8 + 4];
        float du = dt_v * u_v;
        float p = 0.f;
        #pragma unroll
        for (int n = 0; n < 8; ++n) {
            h[n] = fmaf(__expf(dt_v * Av[n]), h[n], du * bl[n]);
            p = fmaf(h[n], cl[n], p);
        }
        p += __shfl_xor(p, 1);
        if (half == 0) {
            float y = fmaf(u_v, Dv, p) * silu_f(rs);
            if (bf16_out) ((__hip_bfloat16*)yout)[r * D_INNER + e] = __float2bfloat16(y);
            else          ((float*)yout)[r * D_INNER + e] = y;
        }
    }
}

extern "C" void kernel_launch(void* const* d_in, const int* in_sizes, int n_in,
                              void* d_out, int out_size, void* d_ws, size_t ws_size,
                              hipStream_t stream)
{
    const float* x      = (const float*)d_in[0];
    const float* W_in   = (const float*)d_in[1];
    const float* conv_w = (const float*)d_in[2];
    const float* conv_b = (const float*)d_in[3];
    const float* W_x    = (const float*)d_in[4];
    const float* W_dt   = (const float*)d_in[5];
    const float* b_dt   = (const float*)d_in[6];
    const float* A_log  = (const float*)d_in[7];
    const float* Dp     = (const float*)d_in[8];
    const float* W_out  = (const float*)d_in[9];
    float* out = (float*)d_out;
    char*  ws  = (char*)d_ws;

    // chunk-state buffers in d_out (dead until final GEMM): 2 x 6,291,456 B
    float* Pbuf = out;
    float* Hend = out + (size_t)CH * NREC;
    const int scan_grid = BATCH * CH * EG;   // 768 blocks

    const bool fast = ws_size >= (size_t)113770496;

    if (fast) {
        // ws layout (bytes) with lifetime aliasing:
        //   resb  @ 0          25,165,824  fp32 [4096,1536]  GEMM1 -> pass3
        //   uc    @ 25165824   25,165,824  fp32 [4096,1536]  conv -> pass3
        //   ucb   @ 50331648   12,582,912  bf16 [4096,1536]  conv -> GEMM2
        //     yb  @ 50331648   (aliases ucb) bf16            pass3 -> GEMM3
        //   dtBC  @ 62914560   25,690,112  fp32 [4096,1568]  GEMM2 -> pass3
        //     xb  @ 62914560    6,291,456  bf16 (pre-GEMM2)
        //     wint@ 69206016    4,718,592  bf16 (pre-GEMM2)
        //   uraw  @ 88604672   25,165,824  fp32 [4096,1536]  GEMM1 -> conv
        //     Weff@ 88604672    9,437,184  fp32 (post-conv)
        //     WcT @ 98041856    5,111,808  bf16 [1664,1536] (post-conv)
        //     wott@ 103153664   2,359,296  bf16 (post-conv)
        //   total 113,770,496
        float* resb = (float*)(ws);
        float* uc   = (float*)(ws + 25165824);
        __hip_bfloat16* ucb  = (__hip_bfloat16*)(ws + 50331648);
        __hip_bfloat16* yb   = (__hip_bfloat16*)(ws + 50331648);
        float* dtBC = (float*)(ws + 62914560);
        __hip_bfloat16* xb   = (__hip_bfloat16*)(ws + 62914560);
        __hip_bfloat16* wint = (__hip_bfloat16*)(ws + 69206016);
        float* uraw = (float*)(ws + 88604672);
        float* Weff = (float*)(ws + 88604672);
        __hip_bfloat16* WcT  = (__hip_bfloat16*)(ws + 98041856);
        __hip_bfloat16* wott = (__hip_bfloat16*)(ws + 103153664);

        // prep + GEMM1: xz = x @ W_in, split into uraw | resb
        cast_bf16<<<(BL * D_MODEL / 4) / 256, 256, 0, stream>>>(x, xb);
        transpose_cast<<<dim3(XZ_W / 32, D_MODEL / 32), 256, 0, stream>>>(
            W_in, wint, D_MODEL, XZ_W, XZ_W);
        gemm_bf16_bt<<<dim3(XZ_W / 128, BL / 128), 256, 0, stream>>>(
            xb, wint, uraw, resb, nullptr, XZ_W, D_MODEL, XZ_W, 1);

        // conv + SiLU -> uc fp32 + ucb bf16
        conv_silu<<<(BL * D_INNER) / 256, 256, 0, stream>>>(
            uraw, conv_w, conv_b, uc, ucb, D_INNER, 1);

        // W_eff = W_x[:, :48] @ W_dt   [1536,1536] K=48 (fp32)
        gemm_f32<<<dim3(D_INNER / 64, D_INNER / 64), 256, 0, stream>>>(
            W_x, W_dt, Weff, nullptr, D_INNER, DT_RANK, SSM_W, D_INNER, D_INNER, 0);
        // WcT rows 0..1535 = W_eff^T; rows 1536..1567 = W_x[:,48:80]^T; 1568+ garbage (unused)
        transpose_cast<<<dim3(D_INNER / 32, D_INNER / 32), 256, 0, stream>>>(
            Weff, WcT, D_INNER, D_INNER, D_INNER);
        transpose_cast<<<dim3(BC_W / 32, D_INNER / 32), 256, 0, stream>>>(
            W_x + DT_RANK, WcT + (size_t)D_INNER * D_INNER, D_INNER, BC_W, SSM_W);

        // GEMM2: dt|B|C = ucb @ W_cat  [4096,1664->1568] K=1536, softplus on dt cols
        gemm_bf16_bt<<<dim3(DTBC_N / 128, BL / 128), 256, 0, stream>>>(
            ucb, WcT, dtBC, nullptr, b_dt, DTBC_N, D_INNER, DTBC_LD, 2);

        // chunked scan
        scan_pass1<<<scan_grid, 256, 0, stream>>>(
            dtBC, DTBC_LD, uc, dtBC + D_INNER, DTBC_LD, A_log, Pbuf, Hend);
        scan_pass2<<<NREC / 256, 256, 0, stream>>>(Pbuf, Hend);
        scan_pass3<<<scan_grid, 256, 0, stream>>>(
            dtBC, DTBC_LD, uc, dtBC + D_INNER, DTBC_LD, resb, D_INNER,
            A_log, Dp, Pbuf, (void*)yb, 1);

        // GEMM3: out = y @ W_out  [4096,768] K=1536
        transpose_cast<<<dim3(D_MODEL / 32, D_INNER / 32), 256, 0, stream>>>(
            W_out, wott, D_INNER, D_MODEL, D_MODEL);
        gemm_bf16_bt<<<dim3(D_MODEL / 128, BL / 128), 256, 0, stream>>>(
            yb, wott, out, nullptr, nullptr, D_MODEL, D_INNER, D_MODEL, 0);
    } else {
        // fp32 fallback (round-2 structure)
        float* xz  = (float*)(ws);
        float* uc  = (float*)(ws + 50331648);
        float* smb = (float*)(ws + 75497472);
        float* dtb = (float*)(ws + 76808192);
        float* yf  = dtb;
        gemm_f32<<<dim3(XZ_W / 64, BL / 64), 256, 0, stream>>>(
            x, W_in, xz, nullptr, XZ_W, D_MODEL, D_MODEL, XZ_W, XZ_W, 0);
        conv_silu<<<(BL * D_INNER) / 256, 256, 0, stream>>>(
            xz, conv_w, conv_b, uc, nullptr, XZ_W, 0);
        gemm_f32<<<dim3(2, BL / 64), 256, 0, stream>>>(
            uc, W_x, smb, nullptr, SSM_W, D_INNER, D_INNER, SSM_W, SSM_W, 0);
        gemm_f32<<<dim3(D_INNER / 64, BL / 64), 256, 0, stream>>>(
            smb, W_dt, dtb, b_dt, D_INNER, DT_RANK, SSM_W, D_INNER, D_INNER, 1);
        scan_pass1<<<scan_grid, 256, 0, stream>>>(
            dtb, D_INNER, uc, smb + DT_RANK, SSM_W, A_log, Pbuf, Hend);
        scan_pass2<<<NREC / 256, 256, 0, stream>>>(Pbuf, Hend);
        scan_pass3<<<scan_grid, 256, 0, stream>>>(
            dtb, D_INNER, uc, smb + DT_RANK, SSM_W, xz + D_INNER, XZ_W,
            A_log, Dp, Pbuf, (void*)yf, 0);
        gemm_f32<<<dim3(D_MODEL / 64, BL / 64), 256, 0, stream>>>(
            yf, W_out, out, nullptr, D_MODEL, D_INNER, D_INNER, D_MODEL, D_MODEL, 0);
    }
}